// Round 3
// baseline (394.139 us; speedup 1.0000x reference)
//
#include <hip/hip_runtime.h>
#include <stdint.h>

// Problem constants (fixed by the reference):
#define BB     16
#define NTOK   16384
#define GG     128
#define NGMAX  128
#define DD     256
#define NTILE  2048             // tokens per tile for rank counting
#define NT     (NTOK / NTILE)   // 8 tiles per sample

typedef unsigned short u16;
typedef unsigned int   u32;

// Workspace layout:
//   pack16[B*N]  (512 KB): per token, (g << 8) | clipped_rank. g=255 => uncovered.
//   hist [B*NT*G] (64 KB): per-tile per-g counts -> exclusive prefix over tiles.

// ---------------------------------------------------------------------------
// Kernel 1: per-token "last g with onehot[.,g] > 0". fp32 onehot row = 512B.
// 8 lanes per token; lane `inner` covers elements {inner*4 + j*32 .. +3},
// j=0..3 (each j-step: 8 lanes read 128B contiguous). Keep the LAST positive
// index = max index over lanes. float > 0  <=>  (int)bits > 0.
// ---------------------------------------------------------------------------
__global__ __launch_bounds__(256) void k_lastg(const float* __restrict__ onehot,
                                               u16* __restrict__ pack) {
    int tid   = threadIdx.x;
    int tn    = blockIdx.x * 32 + (tid >> 3);   // token id in [0, B*N)
    int inner = tid & 7;
    const float* base = onehot + (size_t)tn * GG;

    int best = -1;
#pragma unroll
    for (int j = 0; j < 4; ++j) {
        int e = inner * 4 + j * 32;
        int4 v = *reinterpret_cast<const int4*>(base + e);
        if (v.x > 0) best = e + 0;   // fp32 > 0 <=> int bits > 0 (no NaN/-0 here)
        if (v.y > 0) best = e + 1;
        if (v.z > 0) best = e + 2;
        if (v.w > 0) best = e + 3;
    }
#pragma unroll
    for (int o = 1; o < 8; o <<= 1) {
        int other = __shfl_xor(best, o);
        best = max(best, other);
    }
    if (inner == 0) pack[tn] = (best < 0) ? (u16)0xFF00 : (u16)(best << 8);
}

// ---------------------------------------------------------------------------
// Kernel 2: per-(b,tile,g) count of claimed tokens. One thread per g; all 128
// threads of a block scan the same 4KB pack row (uniform-address -> scalar
// loads, L1-broadcast).
// ---------------------------------------------------------------------------
__global__ __launch_bounds__(128) void k_count(const u16* __restrict__ pack,
                                               u32* __restrict__ hist) {
    int bt = blockIdx.x;              // b*NT + t
    unsigned g = threadIdx.x;         // 0..127
    const u16* row = pack + (size_t)bt * NTILE;
    u32 cnt = 0;
    for (int c = 0; c < NTILE; c += 8) {
        uint4 v = *reinterpret_cast<const uint4*>(row + c);
        cnt += ((v.x >> 8) & 0xFFu) == g;
        cnt += ( v.x >> 24        ) == g;
        cnt += ((v.y >> 8) & 0xFFu) == g;
        cnt += ( v.y >> 24        ) == g;
        cnt += ((v.z >> 8) & 0xFFu) == g;
        cnt += ( v.z >> 24        ) == g;
        cnt += ((v.w >> 8) & 0xFFu) == g;
        cnt += ( v.w >> 24        ) == g;
    }
    hist[bt * GG + g] = cnt;
}

// ---------------------------------------------------------------------------
// Kernel 3: exclusive prefix over the NT tiles per (b,g), in place.
// ---------------------------------------------------------------------------
__global__ __launch_bounds__(256) void k_prefix(u32* __restrict__ hist) {
    int idx = blockIdx.x * 256 + threadIdx.x;    // 0..2047 = b*GG + g
    int b = idx >> 7, g = idx & 127;
    u32 run = 0;
#pragma unroll
    for (int t = 0; t < NT; ++t) {
        u32* p = &hist[(b * NT + t) * GG + g];
        u32 v = *p;
        *p = run;
        run += v;
    }
}

// ---------------------------------------------------------------------------
// Kernel 4: write ranks. Thread (b,t,g) serially re-scans its tile in token
// order; on a match writes (g<<8)|min(rank,127). Concurrent writers touch
// disjoint elements and preserve the hi byte, so interleaving is benign.
// ---------------------------------------------------------------------------
__global__ __launch_bounds__(128) void k_rankw(u16* __restrict__ pack,
                                               const u32* __restrict__ hist) {
    int bt = blockIdx.x;
    unsigned g = threadIdx.x;
    u32 cnt = hist[bt * GG + g];
    u16* row = pack + (size_t)bt * NTILE;
    u16 hi = (u16)(g << 8);
    for (int c = 0; c < NTILE; ++c) {
        if ((unsigned)(row[c] >> 8) == g) {
            u32 k = cnt < (NGMAX - 1) ? cnt : (NGMAX - 1);
            row[c] = (u16)(hi | k);
            cnt++;
        }
    }
}

// ---------------------------------------------------------------------------
// Kernel 5: gather the 1KB fp32 feature row per token. 16 lanes per token,
// 4 x 16B each (per j-step: 16 lanes move 256B contiguous).
// ---------------------------------------------------------------------------
__global__ __launch_bounds__(256) void k_gather(const float* __restrict__ feat,
                                                const u16* __restrict__ pack,
                                                float* __restrict__ out) {
    int tid   = threadIdx.x;
    int token = blockIdx.x * 16 + (tid >> 4);
    int inner = tid & 15;
    int b     = token / NTOK;

    unsigned p = pack[token];
    unsigned g = p >> 8;
    unsigned k = p & 0xFFu;

    float4 vals[4];
    if (g < GG) {
        const float* src = feat + (((size_t)(b * GG + g)) * NGMAX + k) * DD;
#pragma unroll
        for (int j = 0; j < 4; ++j)
            vals[j] = *reinterpret_cast<const float4*>(src + inner * 4 + j * 64);
    } else {
#pragma unroll
        for (int j = 0; j < 4; ++j) vals[j] = make_float4(0.f, 0.f, 0.f, 0.f);
    }
    float* dst = out + (size_t)token * DD;
#pragma unroll
    for (int j = 0; j < 4; ++j)
        *reinterpret_cast<float4*>(dst + inner * 4 + j * 64) = vals[j];
}

// ---------------------------------------------------------------------------
extern "C" void kernel_launch(void* const* d_in, const int* in_sizes, int n_in,
                              void* d_out, int out_size, void* d_ws, size_t ws_size,
                              hipStream_t stream) {
    const float* feat   = (const float*)d_in[0];   // [B,G,NGMAX,D] fp32
    const float* onehot = (const float*)d_in[1];   // [B,N,G] fp32
    float*       out    = (float*)d_out;           // [B,N,D] fp32

    u16* pack = (u16*)d_ws;                                        // 512 KB
    u32* hist = (u32*)((char*)d_ws + (size_t)BB * NTOK * 2);       // 64 KB

    k_lastg <<<BB * NTOK / 32,  256, 0, stream>>>(onehot, pack);
    k_count <<<BB * NT,         128, 0, stream>>>(pack, hist);
    k_prefix<<<8,               256, 0, stream>>>(hist);
    k_rankw <<<BB * NT,         128, 0, stream>>>(pack, hist);
    k_gather<<<BB * NTOK / 16,  256, 0, stream>>>(feat, pack, out);
}

// Round 4
// 136.187 us; speedup vs baseline: 2.8941x; 2.8941x over previous
//
#include <hip/hip_runtime.h>
#include <stdint.h>

// Problem constants (fixed by the reference):
#define BB     16
#define NTOK   16384
#define GG     128
#define NGMAX  128
#define DD     256
#define NCHUNK (NTOK / 64)      // 256 64-token chunks per sample

typedef unsigned short     u16;
typedef unsigned int       u32;
typedef unsigned long long u64;

// Workspace layout:
//   pack16[B*N]        (512 KB): per token, (g << 8) | chunk_rank. g=255 => uncovered.
//   hist  [B][G][NCHUNK] (2 MB): per-chunk per-g counts -> exclusive prefix over chunks.

// ---------------------------------------------------------------------------
// Kernel 1: per-token "last g with onehot[.,g] > 0". fp32 onehot row = 512B.
// 8 lanes per token, 4 x int4 each. float > 0 <=> int bits > 0 (no NaN/-0).
// ---------------------------------------------------------------------------
__global__ __launch_bounds__(256) void k_lastg(const float* __restrict__ onehot,
                                               u16* __restrict__ pack) {
    int tid   = threadIdx.x;
    int tn    = blockIdx.x * 32 + (tid >> 3);   // token id in [0, B*N)
    int inner = tid & 7;
    const float* base = onehot + (size_t)tn * GG;

    int best = -1;
#pragma unroll
    for (int j = 0; j < 4; ++j) {
        int e = inner * 4 + j * 32;
        int4 v = *reinterpret_cast<const int4*>(base + e);
        if (v.x > 0) best = e + 0;
        if (v.y > 0) best = e + 1;
        if (v.z > 0) best = e + 2;
        if (v.w > 0) best = e + 3;
    }
#pragma unroll
    for (int o = 1; o < 8; o <<= 1) {
        int other = __shfl_xor(best, o);
        best = max(best, other);
    }
    if (inner == 0) pack[tn] = (best < 0) ? (u16)0xFF00 : (u16)(best << 8);
}

// ---------------------------------------------------------------------------
// Kernel 2: per-64-token-chunk ranks + full chunk histogram, one wave/chunk.
// 8 ballot bit-planes of g; own rank = popc(same & below). Histogram WITHOUT
// memset: lane l reconstructs counts for g=l and g=l+64 from the planes
// (AND of plane/~plane per target bit; bit7=0 excludes the g=255 sentinel).
// ---------------------------------------------------------------------------
__global__ __launch_bounds__(256) void k_rank64(u16* __restrict__ pack,
                                                u32* __restrict__ hist) {
    int lane  = threadIdx.x & 63;
    int wid   = threadIdx.x >> 6;
    int chunk = blockIdx.x * 4 + wid;           // global chunk id, 0..B*NCHUNK-1
    int b     = chunk >> 8;                     // chunk / NCHUNK
    int cb    = chunk & (NCHUNK - 1);           // chunk within sample
    int token = chunk * 64 + lane;

    unsigned g = pack[token] >> 8;              // 0..127 or 255

    u64 plane[8];
#pragma unroll
    for (int bit = 0; bit < 8; ++bit)
        plane[bit] = __ballot((g >> bit) & 1u);

    u64 same = ~0ull;
#pragma unroll
    for (int bit = 0; bit < 8; ++bit)
        same &= ((g >> bit) & 1u) ? plane[bit] : ~plane[bit];
    u64 below = ((u64)1 << lane) - 1;
    unsigned rank = (unsigned)__popcll(same & below);   // <= 63
    pack[token] = (u16)((g << 8) | rank);

#pragma unroll
    for (int h = 0; h < 2; ++h) {
        unsigned tg = (unsigned)lane + h * 64;  // target g: bit7 == 0 always
        u64 m = ~0ull;
#pragma unroll
        for (int bit = 0; bit < 8; ++bit)
            m &= ((tg >> bit) & 1u) ? plane[bit] : ~plane[bit];
        hist[((size_t)(b * GG + tg)) * NCHUNK + cb] = (u32)__popcll(m);
    }
}

// ---------------------------------------------------------------------------
// Kernel 3: exclusive prefix over the NCHUNK counts per (b,g), one wave each.
// uint4 per lane (contiguous 4KB row), shuffle-up wave scan.
// ---------------------------------------------------------------------------
__global__ __launch_bounds__(64) void k_scan(u32* __restrict__ hist) {
    int pair = blockIdx.x;                      // b*GG + g
    int lane = threadIdx.x;
    u32* row = hist + (size_t)pair * NCHUNK;

    uint4 v = *reinterpret_cast<uint4*>(row + lane * 4);
    u32 s0 = v.x, s1 = s0 + v.y, s2 = s1 + v.z, s3 = s2 + v.w;
    u32 tot = s3, inc = tot;
#pragma unroll
    for (int o = 1; o < 64; o <<= 1) {
        u32 t = __shfl_up(inc, o);
        if (lane >= o) inc += t;
    }
    u32 excl = inc - tot;
    uint4 w;
    w.x = excl;
    w.y = excl + s0;
    w.z = excl + s1;
    w.w = excl + s2;
    *reinterpret_cast<uint4*>(row + lane * 4) = w;
}

// ---------------------------------------------------------------------------
// Kernel 4: gather the 1KB fp32 feature row per token. 16 lanes per token,
// 4 x 16B each. k = chunk_rank + chunk_offset, clipped to NGMAX-1.
// ---------------------------------------------------------------------------
__global__ __launch_bounds__(256) void k_gather(const float* __restrict__ feat,
                                                const u16* __restrict__ pack,
                                                const u32* __restrict__ hist,
                                                float* __restrict__ out) {
    int tid   = threadIdx.x;
    int token = blockIdx.x * 16 + (tid >> 4);
    int inner = tid & 15;
    int b     = token >> 14;                    // token / NTOK
    int n     = token & (NTOK - 1);

    unsigned p = pack[token];
    unsigned g = p >> 8;
    unsigned r = p & 0xFFu;

    float4 vals[4];
    if (g < GG) {
        u32 k = r + hist[((size_t)(b * GG + g)) * NCHUNK + (n >> 6)];
        if (k > NGMAX - 1) k = NGMAX - 1;
        const float* src = feat + (((size_t)(b * GG + g)) * NGMAX + k) * DD;
#pragma unroll
        for (int j = 0; j < 4; ++j)
            vals[j] = *reinterpret_cast<const float4*>(src + inner * 4 + j * 64);
    } else {
#pragma unroll
        for (int j = 0; j < 4; ++j) vals[j] = make_float4(0.f, 0.f, 0.f, 0.f);
    }
    float* dst = out + (size_t)token * DD;
#pragma unroll
    for (int j = 0; j < 4; ++j)
        *reinterpret_cast<float4*>(dst + inner * 4 + j * 64) = vals[j];
}

// ---------------------------------------------------------------------------
extern "C" void kernel_launch(void* const* d_in, const int* in_sizes, int n_in,
                              void* d_out, int out_size, void* d_ws, size_t ws_size,
                              hipStream_t stream) {
    const float* feat   = (const float*)d_in[0];   // [B,G,NGMAX,D] fp32
    const float* onehot = (const float*)d_in[1];   // [B,N,G] fp32
    float*       out    = (float*)d_out;           // [B,N,D] fp32

    u16* pack = (u16*)d_ws;                                        // 512 KB
    u32* hist = (u32*)((char*)d_ws + (size_t)BB * NTOK * 2);       // 2 MB

    k_lastg <<<BB * NTOK / 32,   256, 0, stream>>>(onehot, pack);
    k_rank64<<<BB * NCHUNK / 4,  256, 0, stream>>>(pack, hist);
    k_scan  <<<BB * GG,          64,  0, stream>>>(hist);
    k_gather<<<BB * NTOK / 16,   256, 0, stream>>>(feat, pack, hist, out);
}